// Round 13
// baseline (281.829 us; speedup 1.0000x reference)
//
#include <hip/hip_runtime.h>

typedef float f32x4 __attribute__((ext_vector_type(4)));
typedef short bf16x8 __attribute__((ext_vector_type(8)));
typedef unsigned short u16;
typedef unsigned int u32;

// hw packed cvt: two f32 -> one u32 of 2 bf16 (RNE), single VOP3 instr
__device__ __forceinline__ u32 cvt_pk_bf16(float lo, float hi) {
    u32 r;
    asm("v_cvt_pk_bf16_f32 %0, %1, %2" : "=v"(r) : "v"(lo), "v"(hi));
    return r;
}

// float -> bf16 bits, round-to-nearest-even (cold paths only)
__device__ __forceinline__ u16 f2b(float f) {
    union { float f; u32 u; } v; v.f = f;
    u32 r = v.u + 0x7fffu + ((v.u >> 16) & 1u);
    return (u16)(r >> 16);
}
__device__ __forceinline__ float b2f_lo(u32 p) {
    union { u32 u; float f; } v; v.u = p << 16; return v.f;
}
__device__ __forceinline__ float b2f_hi(u32 p) {
    union { u32 u; float f; } v; v.u = p & 0xffff0000u; return v.f;
}

// shifted softplus via hw transcendentals: log(1+e^x) - log2
__device__ __forceinline__ float ssp(float x) {
    return fmaxf(x, 0.0f) + __logf(1.0f + __expf(-fabsf(x))) - 0.6931471805599453f;
}

// ---------------------------------------------------------------------------
// Convert all weight matrices to bf16, layout [out_c][k] (fw1 K-padded 50->64)
// ---------------------------------------------------------------------------
__global__ void prep_weights(const float* __restrict__ fw1,
                             const float* __restrict__ fw2,
                             const float* __restrict__ w1,
                             const float* __restrict__ w2,
                             const float* __restrict__ w3,
                             u16* __restrict__ out) {
    int t = blockIdx.x * blockDim.x + threadIdx.x;
    if (t < 128 * 64) {
        int c = t >> 6, k = t & 63;
        out[t] = f2b(k < 50 ? fw1[c * 50 + k] : 0.0f);
        return;
    }
    t -= 128 * 64;
    if (t < 16384) { out[8192 + t] = f2b(fw2[t]); return; }
    t -= 16384;
    if (t < 16384) { out[8192 + 16384 + t] = f2b(w1[t]); return; }
    t -= 16384;
    if (t < 16384) { out[8192 + 32768 + t] = f2b(w2[t]); return; }
    t -= 16384;
    if (t < 16384) { out[8192 + 49152 + t] = f2b(w3[t]); return; }
}

// ---------------------------------------------------------------------------
// Generic out = act(in[M,128] @ wT + bias), bf16 MFMA 16x16x32.
// OBF=1 -> bf16 output, else f32.  (used for xh and as fallback pieces)
// ---------------------------------------------------------------------------
template <int ACT, int OBF>
__global__ __launch_bounds__(256, 3) void linear128(
    const float* __restrict__ in, const u16* __restrict__ wb,
    const float* __restrict__ bias, void* __restrict__ outv, int M) {
    __shared__ u16 in_lds[64 * 136];
    __shared__ u16 w_lds[128 * 136];

    const int tid = threadIdx.x;
    const int r0 = blockIdx.x * 64;

    for (int idx = tid; idx < 128 * 16; idx += 256) {
        int c = idx >> 4, kc = (idx & 15) * 8;
        *reinterpret_cast<uint4*>(&w_lds[c * 136 + kc]) =
            *reinterpret_cast<const uint4*>(&wb[c * 128 + kc]);
    }
    for (int idx = tid; idx < 64 * 32; idx += 256) {
        int r = idx >> 5, kc = (idx & 31) * 4;
        int row = r0 + r;
        float4 v = make_float4(0.f, 0.f, 0.f, 0.f);
        if (row < M) v = *reinterpret_cast<const float4*>(&in[(size_t)row * 128 + kc]);
        u32* p = reinterpret_cast<u32*>(&in_lds[r * 136 + kc]);
        p[0] = cvt_pk_bf16(v.x, v.y); p[1] = cvt_pk_bf16(v.z, v.w);
    }
    __syncthreads();

    const int l = tid & 63, w = tid >> 6;
    const int lr = l & 15, lg = l >> 4;

    f32x4 acc[8] = {};
    for (int ks = 0; ks < 4; ++ks) {
        bf16x8 a = *reinterpret_cast<const bf16x8*>(
            &in_lds[(w * 16 + lr) * 136 + ks * 32 + lg * 8]);
        for (int n = 0; n < 8; ++n) {
            bf16x8 b = *reinterpret_cast<const bf16x8*>(
                &w_lds[(n * 16 + lr) * 136 + ks * 32 + lg * 8]);
            acc[n] = __builtin_amdgcn_mfma_f32_16x16x32_bf16(a, b, acc[n], 0, 0, 0);
        }
    }

    for (int n = 0; n < 8; ++n) {
        int c = n * 16 + lr;
        float bv = bias ? bias[c] : 0.0f;
        for (int i = 0; i < 4; ++i) {
            int row = r0 + w * 16 + lg * 4 + i;
            if (row < M) {
                float v = acc[n][i] + bv;
                if (ACT) v = ssp(v);
                if (OBF) ((u16*)outv)[(size_t)row * 128 + c] = f2b(v);
                else     ((float*)outv)[(size_t)row * 128 + c] = v;
            }
        }
    }
}

// ---------------------------------------------------------------------------
// Edge filter MLP v7 (R12, kept): 8 waves x 16-channel slice, 1 barrier per
// 32-edge tile, double-buffered bas/hb, grid-stride persistent.
// ---------------------------------------------------------------------------
__global__ __launch_bounds__(512) void edge_mlp(
    const float* __restrict__ basis, const float* __restrict__ e_ji,
    const u16* __restrict__ fw1b, const u16* __restrict__ fw2b,
    const float* __restrict__ fb1, const float* __restrict__ fb2,
    const int* __restrict__ epos, u16* __restrict__ Wb,
    int E, int nTiles, int stride) {
    __shared__ u16 bas[2][32 * 72];   // 9.2 KB total
    __shared__ u16 hb[2][32 * 136];   // 17.4 KB total

    const int tid = threadIdx.x;
    const int l = tid & 63, w = tid >> 6;   // w in [0,8): channel tile
    const int lr = l & 15, lg = l >> 4;
    const int c8 = lg * 8, c4 = lg * 4;

    bf16x8 wa1[2], wa2[4];
    const u16* p1 = &fw1b[(size_t)(w * 16 + lr) * 64];
    wa1[0] = *reinterpret_cast<const bf16x8*>(p1 + c8);
    wa1[1] = *reinterpret_cast<const bf16x8*>(p1 + 32 + c8);
    const u16* p2 = &fw2b[(size_t)(w * 16 + lr) * 128];
#pragma unroll
    for (int ks = 0; ks < 4; ++ks)
        wa2[ks] = *reinterpret_cast<const bf16x8*>(p2 + ks * 32 + c8);
    const float4 b1v = *reinterpret_cast<const float4*>(&fb1[w * 16 + c4]);
    const float4 b2v = *reinterpret_cast<const float4*>(&fb2[w * 16 + c4]);

    for (int idx = tid; idx < 2 * 32 * 7; idx += 512) {
        int b = idx / 224, rem = idx - b * 224;
        int row = rem / 7, q = rem - row * 7;
        *reinterpret_cast<u32*>(&bas[b][row * 72 + 50 + 2 * q]) = 0u;
    }

    const int srow = tid & 31, cb = tid >> 5;
    const bool has2 = cb < 9;

    int it = blockIdx.x;
    if (it >= nTiles) return;

    {
        int er = it * 32 + srow; if (er >= E) er = E - 1;
        const float* rp = &basis[(size_t)er * 50];
        float2 v0 = *reinterpret_cast<const float2*>(rp + 2 * cb);
        *reinterpret_cast<u32*>(&bas[0][srow * 72 + 2 * cb]) = cvt_pk_bf16(v0.x, v0.y);
        if (has2) {
            float2 v1 = *reinterpret_cast<const float2*>(rp + 2 * (cb + 16));
            *reinterpret_cast<u32*>(&bas[0][srow * 72 + 2 * (cb + 16)]) =
                cvt_pk_bf16(v1.x, v1.y);
        }
    }
    __syncthreads();

    int buf = 0;
    for (; it < nTiles; it += stride, buf ^= 1) {
        const int nxt = it + stride;
        const bool hn = nxt < nTiles;
        float2 stg0, stg1;
        if (hn) {
            int er = nxt * 32 + srow; if (er >= E) er = E - 1;
            const float* rp = &basis[(size_t)er * 50];
            stg0 = *reinterpret_cast<const float2*>(rp + 2 * cb);
            if (has2) stg1 = *reinterpret_cast<const float2*>(rp + 2 * (cb + 16));
        }
        const int er0 = it * 32 + lr, er1 = er0 + 16;
        const int ec0 = er0 < E ? er0 : E - 1;
        const int ec1 = er1 < E ? er1 : E - 1;
        const int ep0 = epos[ec0], ep1 = epos[ec1];
        const float ej0 = e_ji[ec0], ej1 = e_ji[ec1];

        // GEMM1 (K=64)
        f32x4 acc1[2] = {};
#pragma unroll
        for (int ks = 0; ks < 2; ++ks) {
            bf16x8 bb0 = *reinterpret_cast<const bf16x8*>(
                &bas[buf][lr * 72 + ks * 32 + c8]);
            bf16x8 bb1 = *reinterpret_cast<const bf16x8*>(
                &bas[buf][(16 + lr) * 72 + ks * 32 + c8]);
            acc1[0] = __builtin_amdgcn_mfma_f32_16x16x32_bf16(wa1[ks], bb0, acc1[0], 0, 0, 0);
            acc1[1] = __builtin_amdgcn_mfma_f32_16x16x32_bf16(wa1[ks], bb1, acc1[1], 0, 0, 0);
        }
#pragma unroll
        for (int t = 0; t < 2; ++t) {
            u32* d = reinterpret_cast<u32*>(
                &hb[buf][(t * 16 + lr) * 136 + w * 16 + c4]);
            d[0] = cvt_pk_bf16(ssp(acc1[t][0] + b1v.x), ssp(acc1[t][1] + b1v.y));
            d[1] = cvt_pk_bf16(ssp(acc1[t][2] + b1v.z), ssp(acc1[t][3] + b1v.w));
        }
        if (hn) {
            *reinterpret_cast<u32*>(&bas[buf ^ 1][srow * 72 + 2 * cb]) =
                cvt_pk_bf16(stg0.x, stg0.y);
            if (has2)
                *reinterpret_cast<u32*>(&bas[buf ^ 1][srow * 72 + 2 * (cb + 16)]) =
                    cvt_pk_bf16(stg1.x, stg1.y);
        }
        __syncthreads();

        // GEMM2 (K=128)
        f32x4 acc2[2] = {};
#pragma unroll
        for (int ks = 0; ks < 4; ++ks) {
            bf16x8 hb0 = *reinterpret_cast<const bf16x8*>(
                &hb[buf][lr * 136 + ks * 32 + c8]);
            bf16x8 hb1 = *reinterpret_cast<const bf16x8*>(
                &hb[buf][(16 + lr) * 136 + ks * 32 + c8]);
            acc2[0] = __builtin_amdgcn_mfma_f32_16x16x32_bf16(wa2[ks], hb0, acc2[0], 0, 0, 0);
            acc2[1] = __builtin_amdgcn_mfma_f32_16x16x32_bf16(wa2[ks], hb1, acc2[1], 0, 0, 0);
        }
#pragma unroll
        for (int t = 0; t < 2; ++t) {
            const int er = t == 0 ? er0 : er1;
            if (er < E) {
                const float ej = t == 0 ? ej0 : ej1;
                const int pos = t == 0 ? ep0 : ep1;
                const float cv = 0.25f * (__cosf(ej * 0.31415926535897932f) + 1.0f);
                uint2 pk;
                pk.x = cvt_pk_bf16((acc2[t][0] + b2v.x) * cv,
                                   (acc2[t][1] + b2v.y) * cv);
                pk.y = cvt_pk_bf16((acc2[t][2] + b2v.z) * cv,
                                   (acc2[t][3] + b2v.w) * cv);
                *reinterpret_cast<uint2*>(
                    &Wb[(size_t)pos * 128 + w * 16 + c4]) = pk;
            }
        }
    }
}

// ---------------------------------------------------------------------------
// CSR build: histogram -> scan -> fill
// ---------------------------------------------------------------------------
__global__ void hist_kernel(const int* __restrict__ pairs, int* __restrict__ deg, int E) {
    int e = blockIdx.x * blockDim.x + threadIdx.x;
    if (e < E) atomicAdd(&deg[pairs[E + e]], 1);
}

__global__ void scan_a(const int* __restrict__ deg, int* __restrict__ incl,
                       int* __restrict__ bsum, int N) {
    __shared__ int s[256];
    int i = blockIdx.x * 256 + threadIdx.x;
    int v = (i < N) ? deg[i] : 0;
    s[threadIdx.x] = v; __syncthreads();
    for (int off = 1; off < 256; off <<= 1) {
        int t = (threadIdx.x >= off) ? s[threadIdx.x - off] : 0;
        __syncthreads();
        s[threadIdx.x] += t; __syncthreads();
    }
    if (i < N) incl[i] = s[threadIdx.x];
    if (threadIdx.x == 255) bsum[blockIdx.x] = s[255];
}

__global__ void scan_b(int* __restrict__ bsum, int nb) {
    __shared__ int s[256];
    int v = (threadIdx.x < nb) ? bsum[threadIdx.x] : 0;
    s[threadIdx.x] = v; __syncthreads();
    for (int off = 1; off < 256; off <<= 1) {
        int t = (threadIdx.x >= off) ? s[threadIdx.x - off] : 0;
        __syncthreads();
        s[threadIdx.x] += t; __syncthreads();
    }
    if (threadIdx.x < nb) bsum[threadIdx.x] = s[threadIdx.x] - v;  // exclusive
}

__global__ void scan_c(const int* __restrict__ incl, const int* __restrict__ deg,
                       const int* __restrict__ bsum, int* __restrict__ rowst,
                       int* __restrict__ cursor, int N) {
    int i = blockIdx.x * 256 + threadIdx.x;
    if (i < N) {
        int r = incl[i] - deg[i] + bsum[blockIdx.x];
        rowst[i] = r; cursor[i] = r;
    }
}

__global__ void fill_kernel(const int* __restrict__ pairs, int* __restrict__ cursor,
                            int* __restrict__ esrc, int* __restrict__ epos, int E) {
    int e = blockIdx.x * blockDim.x + threadIdx.x;
    if (e < E) {
        int s = pairs[e], d = pairs[E + e];
        int pos = atomicAdd(&cursor[d], 1);
        esrc[pos] = s;
        epos[e] = pos;
    }
}

// ---------------------------------------------------------------------------
// agg_tail: fused aggregation + node tail. One 32-node tile per block,
// 512 threads (8 waves).
// Phase A: wave w aggregates nodes n0+w*4..+3 (R11 quad scheme: 4 edges/iter,
//          uint4 loads, shfl_xor(16,32) reduce), packs bf16 row into LDS ab.
// Phase B: out = ssp(ab @ w2T + b2) @ w3T + b3, 16-ch slice per wave,
//          weights in registers. Kills the 51MB f32 agg round trip.
// ---------------------------------------------------------------------------
__global__ __launch_bounds__(512) void agg_tail(
    const u16* __restrict__ Wb, const u16* __restrict__ xhb,
    const int* __restrict__ rowst, const int* __restrict__ deg,
    const int* __restrict__ esrc, const u16* __restrict__ w2b,
    const u16* __restrict__ w3b, const float* __restrict__ b2,
    const float* __restrict__ b3, float* __restrict__ out, int N) {
    __shared__ u16 ab[32 * 136];   // bf16 aggregated rows
    __shared__ u16 hb[32 * 136];   // bf16 hidden rows

    const int tid = threadIdx.x;
    const int l = tid & 63, w = tid >> 6;   // w in [0,8)
    const int lr = l & 15, lg = l >> 4;
    const int c8 = lg * 8, c4 = lg * 4;
    const int n0 = blockIdx.x * 32;

    // ---- persistent weights: 16-ch slice per wave ----
    bf16x8 wA[4], wB[4];
    const u16* pA = &w2b[(size_t)(w * 16 + lr) * 128];
    const u16* pB = &w3b[(size_t)(w * 16 + lr) * 128];
#pragma unroll
    for (int ks = 0; ks < 4; ++ks) {
        wA[ks] = *reinterpret_cast<const bf16x8*>(pA + ks * 32 + c8);
        wB[ks] = *reinterpret_cast<const bf16x8*>(pB + ks * 32 + c8);
    }
    const float4 b2v = *reinterpret_cast<const float4*>(&b2[w * 16 + c4]);
    const float4 b3v = *reinterpret_cast<const float4*>(&b3[w * 16 + c4]);

    // ---- Phase A: aggregate 4 nodes per wave ----
    const int g = lg;                   // edge slot within quad (0..3)
    const int co = lr * 8;              // 8-channel offset within row

    // prefetch CSR meta for the 4 nodes
    int rs4[4], d4[4];
#pragma unroll
    for (int i = 0; i < 4; ++i) {
        int n = n0 + w * 4 + i;
        int nn = n < N ? n : N - 1;
        rs4[i] = rowst[nn];
        d4[i] = deg[nn];
    }

#pragma unroll
    for (int i = 0; i < 4; ++i) {
        const int rs = rs4[i], d = d4[i];
        const int nq = (d + 3) >> 2;
        const int dm1 = d > 0 ? d - 1 : 0;
        float acc[8] = {0.f, 0.f, 0.f, 0.f, 0.f, 0.f, 0.f, 0.f};

        int srcn = (d > 0) ? esrc[rs + (g < d ? g : dm1)] : 0;
        for (int q = 0; q < nq; ++q) {
            const int k = q * 4 + g;
            const bool val = k < d;
            const int row = rs + (val ? k : dm1);
            const int src = srcn;
            const int kn = (q + 1) * 4 + g;
            if (q + 1 < nq) srcn = esrc[rs + (kn < d ? kn : dm1)];

            uint4 wp = *reinterpret_cast<const uint4*>(&Wb[(size_t)row * 128 + co]);
            uint4 xp = *reinterpret_cast<const uint4*>(&xhb[(size_t)src * 128 + co]);
            if (val) {
                const u32* wu = reinterpret_cast<const u32*>(&wp);
                const u32* xu = reinterpret_cast<const u32*>(&xp);
#pragma unroll
                for (int c = 0; c < 4; ++c) {
                    acc[2 * c]     = fmaf(b2f_lo(xu[c]), b2f_lo(wu[c]), acc[2 * c]);
                    acc[2 * c + 1] = fmaf(b2f_hi(xu[c]), b2f_hi(wu[c]), acc[2 * c + 1]);
                }
            }
        }
#pragma unroll
        for (int c = 0; c < 8; ++c) {
            float v = acc[c];
            v += __shfl_xor(v, 16);
            v += __shfl_xor(v, 32);
            acc[c] = v;
        }
        if (g == 0) {   // lanes 0-15 hold the full row; pack to bf16 LDS
            u32* dst = reinterpret_cast<u32*>(&ab[(w * 4 + i) * 136 + co]);
            dst[0] = cvt_pk_bf16(acc[0], acc[1]);
            dst[1] = cvt_pk_bf16(acc[2], acc[3]);
            dst[2] = cvt_pk_bf16(acc[4], acc[5]);
            dst[3] = cvt_pk_bf16(acc[6], acc[7]);
        }
    }
    __syncthreads();

    // ---- Phase B GEMM1: t = ab @ w2T (K=128), 16-ch slice ----
    f32x4 acc1[2] = {};
#pragma unroll
    for (int ks = 0; ks < 4; ++ks) {
        bf16x8 bb0 = *reinterpret_cast<const bf16x8*>(
            &ab[lr * 136 + ks * 32 + c8]);
        bf16x8 bb1 = *reinterpret_cast<const bf16x8*>(
            &ab[(16 + lr) * 136 + ks * 32 + c8]);
        acc1[0] = __builtin_amdgcn_mfma_f32_16x16x32_bf16(wA[ks], bb0, acc1[0], 0, 0, 0);
        acc1[1] = __builtin_amdgcn_mfma_f32_16x16x32_bf16(wA[ks], bb1, acc1[1], 0, 0, 0);
    }
#pragma unroll
    for (int t = 0; t < 2; ++t) {
        u32* d = reinterpret_cast<u32*>(
            &hb[(t * 16 + lr) * 136 + w * 16 + c4]);
        d[0] = cvt_pk_bf16(ssp(acc1[t][0] + b2v.x), ssp(acc1[t][1] + b2v.y));
        d[1] = cvt_pk_bf16(ssp(acc1[t][2] + b2v.z), ssp(acc1[t][3] + b2v.w));
    }
    __syncthreads();

    // ---- Phase B GEMM2: out = t @ w3T + b3 (K=128) ----
    f32x4 acc2[2] = {};
#pragma unroll
    for (int ks = 0; ks < 4; ++ks) {
        bf16x8 hb0 = *reinterpret_cast<const bf16x8*>(
            &hb[lr * 136 + ks * 32 + c8]);
        bf16x8 hb1 = *reinterpret_cast<const bf16x8*>(
            &hb[(16 + lr) * 136 + ks * 32 + c8]);
        acc2[0] = __builtin_amdgcn_mfma_f32_16x16x32_bf16(wB[ks], hb0, acc2[0], 0, 0, 0);
        acc2[1] = __builtin_amdgcn_mfma_f32_16x16x32_bf16(wB[ks], hb1, acc2[1], 0, 0, 0);
    }
#pragma unroll
    for (int t = 0; t < 2; ++t) {
        const int nd = n0 + t * 16 + lr;
        if (nd < N) {
            float4 o;
            o.x = acc2[t][0] + b3v.x;
            o.y = acc2[t][1] + b3v.y;
            o.z = acc2[t][2] + b3v.z;
            o.w = acc2[t][3] + b3v.w;
            *reinterpret_cast<float4*>(&out[(size_t)nd * 128 + w * 16 + c4]) = o;
        }
    }
}

// ---------------------------------------------------------------------------
// Fallback (R1 path): fused edge kernel with f32 atomics
// ---------------------------------------------------------------------------
__global__ __launch_bounds__(256, 2) void edge_kernel(
    const float* __restrict__ basis, const float* __restrict__ e_ji,
    const int* __restrict__ pairs, const float* __restrict__ xh,
    const u16* __restrict__ fw1b, const u16* __restrict__ fw2b,
    const float* __restrict__ fb1, const float* __restrict__ fb2,
    float* __restrict__ agg, int E) {
    __shared__ u16 hb[64 * 136];
    __shared__ u16 fw1_lds[128 * 72];
    __shared__ u16 fw2_lds[128 * 136];
    __shared__ float cc[64];
    __shared__ int s_src[64];
    __shared__ int s_dst[64];

    const int tid = threadIdx.x;
    const int e0 = blockIdx.x * 64;

    for (int idx = tid; idx < 128 * 8; idx += 256) {
        int c = idx >> 3, kc = (idx & 7) * 8;
        *reinterpret_cast<uint4*>(&fw1_lds[c * 72 + kc]) =
            *reinterpret_cast<const uint4*>(&fw1b[c * 64 + kc]);
    }
    for (int idx = tid; idx < 128 * 16; idx += 256) {
        int c = idx >> 4, kc = (idx & 15) * 8;
        *reinterpret_cast<uint4*>(&fw2_lds[c * 136 + kc]) =
            *reinterpret_cast<const uint4*>(&fw2b[c * 128 + kc]);
    }
    for (int idx = tid; idx < 64 * 64; idx += 256) {
        int e = idx >> 6, k = idx & 63;
        int eg = e0 + e;
        float v = (k < 50 && eg < E) ? basis[(size_t)eg * 50 + k] : 0.0f;
        hb[e * 72 + k] = f2b(v);
    }
    if (tid < 64) {
        int eg = e0 + tid;
        if (eg < E) {
            cc[tid] = 0.25f * (__cosf(e_ji[eg] * 0.31415926535897932f) + 1.0f);
            s_src[tid] = pairs[eg];
            s_dst[tid] = pairs[E + eg];
        } else { cc[tid] = 0.0f; s_src[tid] = 0; s_dst[tid] = 0; }
    }
    __syncthreads();

    const int l = tid & 63, w = tid >> 6;
    const int lr = l & 15, lg = l >> 4;

    f32x4 acc1[8] = {};
    for (int ks = 0; ks < 2; ++ks) {
        bf16x8 a = *reinterpret_cast<const bf16x8*>(
            &hb[(w * 16 + lr) * 72 + ks * 32 + lg * 8]);
        for (int n = 0; n < 8; ++n) {
            bf16x8 b = *reinterpret_cast<const bf16x8*>(
                &fw1_lds[(n * 16 + lr) * 72 + ks * 32 + lg * 8]);
            acc1[n] = __builtin_amdgcn_mfma_f32_16x16x32_bf16(a, b, acc1[n], 0, 0, 0);
        }
    }
    __syncthreads();

    for (int n = 0; n < 8; ++n) {
        int c = n * 16 + lr;
        float bv = fb1[c];
        for (int i = 0; i < 4; ++i) {
            int r = w * 16 + lg * 4 + i;
            hb[r * 136 + c] = f2b(ssp(acc1[n][i] + bv));
        }
    }
    __syncthreads();

    f32x4 acc2[8] = {};
    for (int ks = 0; ks < 4; ++ks) {
        bf16x8 a = *reinterpret_cast<const bf16x8*>(
            &hb[(w * 16 + lr) * 136 + ks * 32 + lg * 8]);
        for (int n = 0; n < 8; ++n) {
            bf16x8 b = *reinterpret_cast<const bf16x8*>(
                &fw2_lds[(n * 16 + lr) * 136 + ks * 32 + lg * 8]);
            acc2[n] = __builtin_amdgcn_mfma_f32_16x16x32_bf16(a, b, acc2[n], 0, 0, 0);
        }
    }

    for (int n = 0; n < 8; ++n) {
        int c = n * 16 + lr;
        float bv = fb2[c];
        for (int i = 0; i < 4; ++i) {
            int eloc = w * 16 + lg * 4 + i;
            if (e0 + eloc < E) {
                float Wv = (acc2[n][i] + bv) * cc[eloc];
                float val = xh[(size_t)s_src[eloc] * 128 + c] * Wv;
                unsafeAtomicAdd(&agg[(size_t)s_dst[eloc] * 128 + c], val);
            }
        }
    }
}

extern "C" void kernel_launch(void* const* d_in, const int* in_sizes, int n_in,
                              void* d_out, int out_size, void* d_ws, size_t ws_size,
                              hipStream_t stream) {
    const float* x      = (const float*)d_in[0];
    const int*   pairs  = (const int*)d_in[1];
    const float* e_ji   = (const float*)d_in[2];
    const float* basis  = (const float*)d_in[3];
    const float* fw1    = (const float*)d_in[4];
    const float* fb1    = (const float*)d_in[5];
    const float* fw2    = (const float*)d_in[6];
    const float* fb2    = (const float*)d_in[7];
    const float* w1     = (const float*)d_in[8];
    const float* w2     = (const float*)d_in[9];
    const float* b2     = (const float*)d_in[10];
    const float* w3     = (const float*)d_in[11];
    const float* b3     = (const float*)d_in[12];
    float* out = (float*)d_out;

    const int N = in_sizes[0] / 128;
    const int E = in_sizes[2];
    const int nodeBlocks = (N + 63) / 64;
    const int nchunks = (N + 255) / 256;
    char* ws = (char*)d_ws;

    size_t off = 0;
    auto nxt = [&](size_t bytes) {
        size_t o = off; off = (off + bytes + 255) & ~(size_t)255; return o;
    };
    u16*   Wb     = (u16*)  (ws + nxt((size_t)E * 128 * 2));
    u16*   xhb    = (u16*)  (ws + nxt((size_t)N * 128 * 2));
    float* agg    = (float*)(ws + nxt((size_t)N * 128 * 4));
    u16*   wb     = (u16*)  (ws + nxt(81920 * 2));
    int*   deg    = (int*)  (ws + nxt((size_t)N * 4));
    int*   incl   = (int*)  (ws + nxt((size_t)N * 4));
    int*   rowst  = (int*)  (ws + nxt((size_t)N * 4));
    int*   cursor = (int*)  (ws + nxt((size_t)N * 4));
    int*   bsum   = (int*)  (ws + nxt(1024));
    int*   esrc   = (int*)  (ws + nxt((size_t)E * 4));
    int*   epos   = (int*)  (ws + nxt((size_t)E * 4));
    const size_t needed = off;

    const u16* fw1b = wb;
    const u16* fw2b = wb + 8192;
    const u16* w1b  = wb + 8192 + 16384;
    const u16* w2b  = wb + 8192 + 32768;
    const u16* w3b  = wb + 8192 + 49152;

    if (ws_size >= needed && nchunks <= 256) {
        prep_weights<<<288, 256, 0, stream>>>(fw1, fw2, w1, w2, w3, wb);
        hipMemsetAsync(deg, 0, (size_t)N * 4, stream);

        linear128<0, 1><<<nodeBlocks, 256, 0, stream>>>(x, w1b, nullptr, xhb, N);

        hist_kernel<<<(E + 255) / 256, 256, 0, stream>>>(pairs, deg, E);
        scan_a<<<nchunks, 256, 0, stream>>>(deg, incl, bsum, N);
        scan_b<<<1, 256, 0, stream>>>(bsum, nchunks);
        scan_c<<<nchunks, 256, 0, stream>>>(incl, deg, bsum, rowst, cursor, N);
        fill_kernel<<<(E + 255) / 256, 256, 0, stream>>>(pairs, cursor, esrc, epos, E);

        const int nTiles = (E + 31) / 32;
        const int gridE = nTiles < 1024 ? nTiles : 1024;
        edge_mlp<<<gridE, 512, 0, stream>>>(basis, e_ji, fw1b, fw2b,
                                            fb1, fb2, epos, Wb, E, nTiles, gridE);

        const int ntT = (N + 31) / 32;
        agg_tail<<<ntT, 512, 0, stream>>>(Wb, xhb, rowst, deg, esrc,
                                          w2b, w3b, b2, b3, out, N);
    } else {
        const size_t nodeBytes = (size_t)N * 128 * sizeof(float);
        float* xhf   = (float*)ws;
        float* aggf  = (float*)(ws + nodeBytes);
        u16*   wbf   = (u16*)(ws + 2 * nodeBytes);
        const u16* ffw1b = wbf;
        const u16* ffw2b = wbf + 8192;
        const u16* fw1bw = wbf + 8192 + 16384;
        const u16* fw2bw = wbf + 8192 + 32768;
        const u16* fw3bw = wbf + 8192 + 49152;

        prep_weights<<<288, 256, 0, stream>>>(fw1, fw2, w1, w2, w3, wbf);
        hipMemsetAsync(aggf, 0, nodeBytes, stream);
        linear128<0, 0><<<nodeBlocks, 256, 0, stream>>>(x, fw1bw, nullptr, xhf, N);
        edge_kernel<<<(E + 63) / 64, 256, 0, stream>>>(basis, e_ji, pairs, xhf,
                                                       ffw1b, ffw2b, fb1, fb2, aggf, E);
        linear128<1, 0><<<nodeBlocks, 256, 0, stream>>>(aggf, fw2bw, b2, out, N);
        linear128<0, 0><<<nodeBlocks, 256, 0, stream>>>(out, fw3bw, b3, out, N);
    }
}

// Round 14
// 264.446 us; speedup vs baseline: 1.0657x; 1.0657x over previous
//
#include <hip/hip_runtime.h>

typedef float f32x4 __attribute__((ext_vector_type(4)));
typedef short bf16x8 __attribute__((ext_vector_type(8)));
typedef unsigned short u16;
typedef unsigned int u32;

// hw packed cvt: two f32 -> one u32 of 2 bf16 (RNE), single VOP3 instr
__device__ __forceinline__ u32 cvt_pk_bf16(float lo, float hi) {
    u32 r;
    asm("v_cvt_pk_bf16_f32 %0, %1, %2" : "=v"(r) : "v"(lo), "v"(hi));
    return r;
}

// float -> bf16 bits, round-to-nearest-even (cold paths only)
__device__ __forceinline__ u16 f2b(float f) {
    union { float f; u32 u; } v; v.f = f;
    u32 r = v.u + 0x7fffu + ((v.u >> 16) & 1u);
    return (u16)(r >> 16);
}
__device__ __forceinline__ float b2f_lo(u32 p) {
    union { u32 u; float f; } v; v.u = p << 16; return v.f;
}
__device__ __forceinline__ float b2f_hi(u32 p) {
    union { u32 u; float f; } v; v.u = p & 0xffff0000u; return v.f;
}

// shifted softplus via hw transcendentals: log(1+e^x) - log2
__device__ __forceinline__ float ssp(float x) {
    return fmaxf(x, 0.0f) + __logf(1.0f + __expf(-fabsf(x))) - 0.6931471805599453f;
}

// ---------------------------------------------------------------------------
// Convert all weight matrices to bf16, layout [out_c][k] (fw1 K-padded 50->64)
// ---------------------------------------------------------------------------
__global__ void prep_weights(const float* __restrict__ fw1,
                             const float* __restrict__ fw2,
                             const float* __restrict__ w1,
                             const float* __restrict__ w2,
                             const float* __restrict__ w3,
                             u16* __restrict__ out) {
    int t = blockIdx.x * blockDim.x + threadIdx.x;
    if (t < 128 * 64) {
        int c = t >> 6, k = t & 63;
        out[t] = f2b(k < 50 ? fw1[c * 50 + k] : 0.0f);
        return;
    }
    t -= 128 * 64;
    if (t < 16384) { out[8192 + t] = f2b(fw2[t]); return; }
    t -= 16384;
    if (t < 16384) { out[8192 + 16384 + t] = f2b(w1[t]); return; }
    t -= 16384;
    if (t < 16384) { out[8192 + 32768 + t] = f2b(w2[t]); return; }
    t -= 16384;
    if (t < 16384) { out[8192 + 49152 + t] = f2b(w3[t]); return; }
}

// ---------------------------------------------------------------------------
// Generic out = act(in[M,128] @ wT + bias), bf16 MFMA 16x16x32.
// OBF=1 -> bf16 output, else f32.  (used for xh and as fallback pieces)
// ---------------------------------------------------------------------------
template <int ACT, int OBF>
__global__ __launch_bounds__(256, 3) void linear128(
    const float* __restrict__ in, const u16* __restrict__ wb,
    const float* __restrict__ bias, void* __restrict__ outv, int M) {
    __shared__ u16 in_lds[64 * 136];
    __shared__ u16 w_lds[128 * 136];

    const int tid = threadIdx.x;
    const int r0 = blockIdx.x * 64;

    for (int idx = tid; idx < 128 * 16; idx += 256) {
        int c = idx >> 4, kc = (idx & 15) * 8;
        *reinterpret_cast<uint4*>(&w_lds[c * 136 + kc]) =
            *reinterpret_cast<const uint4*>(&wb[c * 128 + kc]);
    }
    for (int idx = tid; idx < 64 * 32; idx += 256) {
        int r = idx >> 5, kc = (idx & 31) * 4;
        int row = r0 + r;
        float4 v = make_float4(0.f, 0.f, 0.f, 0.f);
        if (row < M) v = *reinterpret_cast<const float4*>(&in[(size_t)row * 128 + kc]);
        u32* p = reinterpret_cast<u32*>(&in_lds[r * 136 + kc]);
        p[0] = cvt_pk_bf16(v.x, v.y); p[1] = cvt_pk_bf16(v.z, v.w);
    }
    __syncthreads();

    const int l = tid & 63, w = tid >> 6;
    const int lr = l & 15, lg = l >> 4;

    f32x4 acc[8] = {};
    for (int ks = 0; ks < 4; ++ks) {
        bf16x8 a = *reinterpret_cast<const bf16x8*>(
            &in_lds[(w * 16 + lr) * 136 + ks * 32 + lg * 8]);
        for (int n = 0; n < 8; ++n) {
            bf16x8 b = *reinterpret_cast<const bf16x8*>(
                &w_lds[(n * 16 + lr) * 136 + ks * 32 + lg * 8]);
            acc[n] = __builtin_amdgcn_mfma_f32_16x16x32_bf16(a, b, acc[n], 0, 0, 0);
        }
    }

    for (int n = 0; n < 8; ++n) {
        int c = n * 16 + lr;
        float bv = bias ? bias[c] : 0.0f;
        for (int i = 0; i < 4; ++i) {
            int row = r0 + w * 16 + lg * 4 + i;
            if (row < M) {
                float v = acc[n][i] + bv;
                if (ACT) v = ssp(v);
                if (OBF) ((u16*)outv)[(size_t)row * 128 + c] = f2b(v);
                else     ((float*)outv)[(size_t)row * 128 + c] = v;
            }
        }
    }
}

// ---------------------------------------------------------------------------
// Edge filter MLP v7 (R12, kept): 8 waves x 16-channel slice, 1 barrier per
// 32-edge tile, double-buffered bas/hb, grid-stride persistent.
// ---------------------------------------------------------------------------
__global__ __launch_bounds__(512) void edge_mlp(
    const float* __restrict__ basis, const float* __restrict__ e_ji,
    const u16* __restrict__ fw1b, const u16* __restrict__ fw2b,
    const float* __restrict__ fb1, const float* __restrict__ fb2,
    const int* __restrict__ epos, u16* __restrict__ Wb,
    int E, int nTiles, int stride) {
    __shared__ u16 bas[2][32 * 72];   // 9.2 KB total
    __shared__ u16 hb[2][32 * 136];   // 17.4 KB total

    const int tid = threadIdx.x;
    const int l = tid & 63, w = tid >> 6;   // w in [0,8): channel tile
    const int lr = l & 15, lg = l >> 4;
    const int c8 = lg * 8, c4 = lg * 4;

    bf16x8 wa1[2], wa2[4];
    const u16* p1 = &fw1b[(size_t)(w * 16 + lr) * 64];
    wa1[0] = *reinterpret_cast<const bf16x8*>(p1 + c8);
    wa1[1] = *reinterpret_cast<const bf16x8*>(p1 + 32 + c8);
    const u16* p2 = &fw2b[(size_t)(w * 16 + lr) * 128];
#pragma unroll
    for (int ks = 0; ks < 4; ++ks)
        wa2[ks] = *reinterpret_cast<const bf16x8*>(p2 + ks * 32 + c8);
    const float4 b1v = *reinterpret_cast<const float4*>(&fb1[w * 16 + c4]);
    const float4 b2v = *reinterpret_cast<const float4*>(&fb2[w * 16 + c4]);

    for (int idx = tid; idx < 2 * 32 * 7; idx += 512) {
        int b = idx / 224, rem = idx - b * 224;
        int row = rem / 7, q = rem - row * 7;
        *reinterpret_cast<u32*>(&bas[b][row * 72 + 50 + 2 * q]) = 0u;
    }

    const int srow = tid & 31, cb = tid >> 5;
    const bool has2 = cb < 9;

    int it = blockIdx.x;
    if (it >= nTiles) return;

    {
        int er = it * 32 + srow; if (er >= E) er = E - 1;
        const float* rp = &basis[(size_t)er * 50];
        float2 v0 = *reinterpret_cast<const float2*>(rp + 2 * cb);
        *reinterpret_cast<u32*>(&bas[0][srow * 72 + 2 * cb]) = cvt_pk_bf16(v0.x, v0.y);
        if (has2) {
            float2 v1 = *reinterpret_cast<const float2*>(rp + 2 * (cb + 16));
            *reinterpret_cast<u32*>(&bas[0][srow * 72 + 2 * (cb + 16)]) =
                cvt_pk_bf16(v1.x, v1.y);
        }
    }
    __syncthreads();

    int buf = 0;
    for (; it < nTiles; it += stride, buf ^= 1) {
        const int nxt = it + stride;
        const bool hn = nxt < nTiles;
        float2 stg0, stg1;
        if (hn) {
            int er = nxt * 32 + srow; if (er >= E) er = E - 1;
            const float* rp = &basis[(size_t)er * 50];
            stg0 = *reinterpret_cast<const float2*>(rp + 2 * cb);
            if (has2) stg1 = *reinterpret_cast<const float2*>(rp + 2 * (cb + 16));
        }
        const int er0 = it * 32 + lr, er1 = er0 + 16;
        const int ec0 = er0 < E ? er0 : E - 1;
        const int ec1 = er1 < E ? er1 : E - 1;
        const int ep0 = epos[ec0], ep1 = epos[ec1];
        const float ej0 = e_ji[ec0], ej1 = e_ji[ec1];

        // GEMM1 (K=64)
        f32x4 acc1[2] = {};
#pragma unroll
        for (int ks = 0; ks < 2; ++ks) {
            bf16x8 bb0 = *reinterpret_cast<const bf16x8*>(
                &bas[buf][lr * 72 + ks * 32 + c8]);
            bf16x8 bb1 = *reinterpret_cast<const bf16x8*>(
                &bas[buf][(16 + lr) * 72 + ks * 32 + c8]);
            acc1[0] = __builtin_amdgcn_mfma_f32_16x16x32_bf16(wa1[ks], bb0, acc1[0], 0, 0, 0);
            acc1[1] = __builtin_amdgcn_mfma_f32_16x16x32_bf16(wa1[ks], bb1, acc1[1], 0, 0, 0);
        }
#pragma unroll
        for (int t = 0; t < 2; ++t) {
            u32* d = reinterpret_cast<u32*>(
                &hb[buf][(t * 16 + lr) * 136 + w * 16 + c4]);
            d[0] = cvt_pk_bf16(ssp(acc1[t][0] + b1v.x), ssp(acc1[t][1] + b1v.y));
            d[1] = cvt_pk_bf16(ssp(acc1[t][2] + b1v.z), ssp(acc1[t][3] + b1v.w));
        }
        if (hn) {
            *reinterpret_cast<u32*>(&bas[buf ^ 1][srow * 72 + 2 * cb]) =
                cvt_pk_bf16(stg0.x, stg0.y);
            if (has2)
                *reinterpret_cast<u32*>(&bas[buf ^ 1][srow * 72 + 2 * (cb + 16)]) =
                    cvt_pk_bf16(stg1.x, stg1.y);
        }
        __syncthreads();

        // GEMM2 (K=128)
        f32x4 acc2[2] = {};
#pragma unroll
        for (int ks = 0; ks < 4; ++ks) {
            bf16x8 hb0 = *reinterpret_cast<const bf16x8*>(
                &hb[buf][lr * 136 + ks * 32 + c8]);
            bf16x8 hb1 = *reinterpret_cast<const bf16x8*>(
                &hb[buf][(16 + lr) * 136 + ks * 32 + c8]);
            acc2[0] = __builtin_amdgcn_mfma_f32_16x16x32_bf16(wa2[ks], hb0, acc2[0], 0, 0, 0);
            acc2[1] = __builtin_amdgcn_mfma_f32_16x16x32_bf16(wa2[ks], hb1, acc2[1], 0, 0, 0);
        }
#pragma unroll
        for (int t = 0; t < 2; ++t) {
            const int er = t == 0 ? er0 : er1;
            if (er < E) {
                const float ej = t == 0 ? ej0 : ej1;
                const int pos = t == 0 ? ep0 : ep1;
                const float cv = 0.25f * (__cosf(ej * 0.31415926535897932f) + 1.0f);
                uint2 pk;
                pk.x = cvt_pk_bf16((acc2[t][0] + b2v.x) * cv,
                                   (acc2[t][1] + b2v.y) * cv);
                pk.y = cvt_pk_bf16((acc2[t][2] + b2v.z) * cv,
                                   (acc2[t][3] + b2v.w) * cv);
                *reinterpret_cast<uint2*>(
                    &Wb[(size_t)pos * 128 + w * 16 + c4]) = pk;
            }
        }
    }
}

// ---------------------------------------------------------------------------
// Fused node tail: out = ssp(aggb @ w2T + b2) @ w3T + b3.
// aggb is bf16 -> staging is plain uint4 copies (no cvt).
// ---------------------------------------------------------------------------
__global__ __launch_bounds__(256) void fused_tail(
    const u16* __restrict__ aggb, const u16* __restrict__ w2b,
    const u16* __restrict__ w3b, const float* __restrict__ b2,
    const float* __restrict__ b3, float* __restrict__ out,
    int N, int nTiles, int stride) {
    __shared__ u16 bas[2][32 * 136];
    __shared__ u16 hb[2][32 * 136];

    const int tid = threadIdx.x;
    const int l = tid & 63, w = tid >> 6;
    const int lr = l & 15, lg = l >> 4;
    const int c8 = lg * 8, c4 = lg * 4;

    bf16x8 wA[2][4], wB[2][4];
    float4 b2v[2], b3v[2];
#pragma unroll
    for (int i = 0; i < 2; ++i) {
        const u16* pA = &w2b[(size_t)((w * 2 + i) * 16 + lr) * 128];
        const u16* pB = &w3b[(size_t)((w * 2 + i) * 16 + lr) * 128];
#pragma unroll
        for (int ks = 0; ks < 4; ++ks) {
            wA[i][ks] = *reinterpret_cast<const bf16x8*>(pA + ks * 32 + c8);
            wB[i][ks] = *reinterpret_cast<const bf16x8*>(pB + ks * 32 + c8);
        }
        b2v[i] = *reinterpret_cast<const float4*>(&b2[(w * 2 + i) * 16 + c4]);
        b3v[i] = *reinterpret_cast<const float4*>(&b3[(w * 2 + i) * 16 + c4]);
    }

    // staging map: row = tid&31, uint4-chunk cb = tid>>5 (8 chunks of 8 u16)
    const int srow = tid & 31, cb = tid >> 5;

    int it = blockIdx.x;
    if (it >= nTiles) return;

    {
        int nd = it * 32 + srow; if (nd >= N) nd = N - 1;
        *reinterpret_cast<uint4*>(&bas[0][srow * 136 + cb * 8]) =
            *reinterpret_cast<const uint4*>(&aggb[(size_t)nd * 128 + cb * 8]);
        *reinterpret_cast<uint4*>(&bas[0][srow * 136 + 64 + cb * 8]) =
            *reinterpret_cast<const uint4*>(&aggb[(size_t)nd * 128 + 64 + cb * 8]);
    }
    __syncthreads();

    int buf = 0;
    for (; it < nTiles; it += stride, buf ^= 1) {
        const int nxt = it + stride;
        const bool hn = nxt < nTiles;
        uint4 stg0, stg1;
        if (hn) {
            int nd = nxt * 32 + srow; if (nd >= N) nd = N - 1;
            stg0 = *reinterpret_cast<const uint4*>(&aggb[(size_t)nd * 128 + cb * 8]);
            stg1 = *reinterpret_cast<const uint4*>(&aggb[(size_t)nd * 128 + 64 + cb * 8]);
        }

        // GEMM1: t = aggb @ w2T (K=128)
        f32x4 acc1[2][2] = {};
#pragma unroll
        for (int ks = 0; ks < 4; ++ks) {
            bf16x8 bb0 = *reinterpret_cast<const bf16x8*>(
                &bas[buf][lr * 136 + ks * 32 + c8]);
            bf16x8 bb1 = *reinterpret_cast<const bf16x8*>(
                &bas[buf][(16 + lr) * 136 + ks * 32 + c8]);
#pragma unroll
            for (int i = 0; i < 2; ++i) {
                acc1[0][i] = __builtin_amdgcn_mfma_f32_16x16x32_bf16(wA[i][ks], bb0, acc1[0][i], 0, 0, 0);
                acc1[1][i] = __builtin_amdgcn_mfma_f32_16x16x32_bf16(wA[i][ks], bb1, acc1[1][i], 0, 0, 0);
            }
        }
        // ssp -> hb[buf]
#pragma unroll
        for (int t = 0; t < 2; ++t) {
#pragma unroll
            for (int i = 0; i < 2; ++i) {
                u32* d = reinterpret_cast<u32*>(
                    &hb[buf][(t * 16 + lr) * 136 + (w * 2 + i) * 16 + c4]);
                d[0] = cvt_pk_bf16(ssp(acc1[t][i][0] + b2v[i].x),
                                   ssp(acc1[t][i][1] + b2v[i].y));
                d[1] = cvt_pk_bf16(ssp(acc1[t][i][2] + b2v[i].z),
                                   ssp(acc1[t][i][3] + b2v[i].w));
            }
        }
        if (hn) {
            *reinterpret_cast<uint4*>(&bas[buf ^ 1][srow * 136 + cb * 8]) = stg0;
            *reinterpret_cast<uint4*>(&bas[buf ^ 1][srow * 136 + 64 + cb * 8]) = stg1;
        }
        __syncthreads();

        // GEMM2: out = t @ w3T (K=128)
        f32x4 acc2[2][2] = {};
#pragma unroll
        for (int ks = 0; ks < 4; ++ks) {
            bf16x8 hb0 = *reinterpret_cast<const bf16x8*>(
                &hb[buf][lr * 136 + ks * 32 + c8]);
            bf16x8 hb1 = *reinterpret_cast<const bf16x8*>(
                &hb[buf][(16 + lr) * 136 + ks * 32 + c8]);
#pragma unroll
            for (int i = 0; i < 2; ++i) {
                acc2[0][i] = __builtin_amdgcn_mfma_f32_16x16x32_bf16(wB[i][ks], hb0, acc2[0][i], 0, 0, 0);
                acc2[1][i] = __builtin_amdgcn_mfma_f32_16x16x32_bf16(wB[i][ks], hb1, acc2[1][i], 0, 0, 0);
            }
        }
#pragma unroll
        for (int t = 0; t < 2; ++t) {
            int nd = it * 32 + t * 16 + lr;
            if (nd < N) {
#pragma unroll
                for (int i = 0; i < 2; ++i) {
                    float4 o;
                    o.x = acc2[t][i][0] + b3v[i].x;
                    o.y = acc2[t][i][1] + b3v[i].y;
                    o.z = acc2[t][i][2] + b3v[i].z;
                    o.w = acc2[t][i][3] + b3v[i].w;
                    *reinterpret_cast<float4*>(
                        &out[(size_t)nd * 128 + (w * 2 + i) * 16 + c4]) = o;
                }
            }
        }
    }
}

// ---------------------------------------------------------------------------
// CSR build: histogram -> scan -> fill
// ---------------------------------------------------------------------------
__global__ void hist_kernel(const int* __restrict__ pairs, int* __restrict__ deg, int E) {
    int e = blockIdx.x * blockDim.x + threadIdx.x;
    if (e < E) atomicAdd(&deg[pairs[E + e]], 1);
}

__global__ void scan_a(const int* __restrict__ deg, int* __restrict__ incl,
                       int* __restrict__ bsum, int N) {
    __shared__ int s[256];
    int i = blockIdx.x * 256 + threadIdx.x;
    int v = (i < N) ? deg[i] : 0;
    s[threadIdx.x] = v; __syncthreads();
    for (int off = 1; off < 256; off <<= 1) {
        int t = (threadIdx.x >= off) ? s[threadIdx.x - off] : 0;
        __syncthreads();
        s[threadIdx.x] += t; __syncthreads();
    }
    if (i < N) incl[i] = s[threadIdx.x];
    if (threadIdx.x == 255) bsum[blockIdx.x] = s[255];
}

__global__ void scan_b(int* __restrict__ bsum, int nb) {
    __shared__ int s[256];
    int v = (threadIdx.x < nb) ? bsum[threadIdx.x] : 0;
    s[threadIdx.x] = v; __syncthreads();
    for (int off = 1; off < 256; off <<= 1) {
        int t = (threadIdx.x >= off) ? s[threadIdx.x - off] : 0;
        __syncthreads();
        s[threadIdx.x] += t; __syncthreads();
    }
    if (threadIdx.x < nb) bsum[threadIdx.x] = s[threadIdx.x] - v;  // exclusive
}

__global__ void scan_c(const int* __restrict__ incl, const int* __restrict__ deg,
                       const int* __restrict__ bsum, int* __restrict__ rowst,
                       int* __restrict__ cursor, int N) {
    int i = blockIdx.x * 256 + threadIdx.x;
    if (i < N) {
        int r = incl[i] - deg[i] + bsum[blockIdx.x];
        rowst[i] = r; cursor[i] = r;
    }
}

__global__ void fill_kernel(const int* __restrict__ pairs, int* __restrict__ cursor,
                            int* __restrict__ esrc, int* __restrict__ epos, int E) {
    int e = blockIdx.x * blockDim.x + threadIdx.x;
    if (e < E) {
        int s = pairs[e], d = pairs[E + e];
        int pos = atomicAdd(&cursor[d], 1);
        esrc[pos] = s;
        epos[e] = pos;
    }
}

// ---------------------------------------------------------------------------
// Aggregate v3: one wave per node, 4 edges/iter (R11 scheme), bf16 output
// (lanes 0-15 pack via cvt_pk; the tail staged to bf16 anyway -> identical
// numerics, half the intermediate traffic).
// ---------------------------------------------------------------------------
__global__ __launch_bounds__(256) void aggregate(
    const u16* __restrict__ Wb, const u16* __restrict__ xhb,
    const int* __restrict__ rowst, const int* __restrict__ deg,
    const int* __restrict__ esrc, u16* __restrict__ aggb, int N) {
    const int w = threadIdx.x >> 6, lane = threadIdx.x & 63;
    const int n = blockIdx.x * 4 + w;
    if (n >= N) return;
    const int rs = rowst[n], d = deg[n];
    const int g = lane >> 4;            // edge slot within quad
    const int co = (lane & 15) * 8;     // 8-channel offset within row
    float acc[8] = {0.f, 0.f, 0.f, 0.f, 0.f, 0.f, 0.f, 0.f};
    const int nq = (d + 3) >> 2;
    const int dm1 = d > 0 ? d - 1 : 0;

    int srcn = (d > 0) ? esrc[rs + (g < d ? g : dm1)] : 0;
    for (int q = 0; q < nq; ++q) {
        const int k = q * 4 + g;
        const bool val = k < d;
        const int row = rs + (val ? k : dm1);
        const int src = srcn;
        const int kn = (q + 1) * 4 + g;
        if (q + 1 < nq) srcn = esrc[rs + (kn < d ? kn : dm1)];

        uint4 wp = *reinterpret_cast<const uint4*>(&Wb[(size_t)row * 128 + co]);
        uint4 xp = *reinterpret_cast<const uint4*>(&xhb[(size_t)src * 128 + co]);
        if (val) {
            const u32* wu = reinterpret_cast<const u32*>(&wp);
            const u32* xu = reinterpret_cast<const u32*>(&xp);
#pragma unroll
            for (int c = 0; c < 4; ++c) {
                acc[2 * c]     = fmaf(b2f_lo(xu[c]), b2f_lo(wu[c]), acc[2 * c]);
                acc[2 * c + 1] = fmaf(b2f_hi(xu[c]), b2f_hi(wu[c]), acc[2 * c + 1]);
            }
        }
    }
#pragma unroll
    for (int c = 0; c < 8; ++c) {
        float v = acc[c];
        v += __shfl_xor(v, 16);
        v += __shfl_xor(v, 32);
        acc[c] = v;
    }
    if (g == 0) {   // lanes 0-15: pack row to bf16, 16B coalesced store
        uint4 pk;
        pk.x = cvt_pk_bf16(acc[0], acc[1]);
        pk.y = cvt_pk_bf16(acc[2], acc[3]);
        pk.z = cvt_pk_bf16(acc[4], acc[5]);
        pk.w = cvt_pk_bf16(acc[6], acc[7]);
        *reinterpret_cast<uint4*>(&aggb[(size_t)n * 128 + co]) = pk;
    }
}

// ---------------------------------------------------------------------------
// Fallback (R1 path): fused edge kernel with f32 atomics
// ---------------------------------------------------------------------------
__global__ __launch_bounds__(256, 2) void edge_kernel(
    const float* __restrict__ basis, const float* __restrict__ e_ji,
    const int* __restrict__ pairs, const float* __restrict__ xh,
    const u16* __restrict__ fw1b, const u16* __restrict__ fw2b,
    const float* __restrict__ fb1, const float* __restrict__ fb2,
    float* __restrict__ agg, int E) {
    __shared__ u16 hb[64 * 136];
    __shared__ u16 fw1_lds[128 * 72];
    __shared__ u16 fw2_lds[128 * 136];
    __shared__ float cc[64];
    __shared__ int s_src[64];
    __shared__ int s_dst[64];

    const int tid = threadIdx.x;
    const int e0 = blockIdx.x * 64;

    for (int idx = tid; idx < 128 * 8; idx += 256) {
        int c = idx >> 3, kc = (idx & 7) * 8;
        *reinterpret_cast<uint4*>(&fw1_lds[c * 72 + kc]) =
            *reinterpret_cast<const uint4*>(&fw1b[c * 64 + kc]);
    }
    for (int idx = tid; idx < 128 * 16; idx += 256) {
        int c = idx >> 4, kc = (idx & 15) * 8;
        *reinterpret_cast<uint4*>(&fw2_lds[c * 136 + kc]) =
            *reinterpret_cast<const uint4*>(&fw2b[c * 128 + kc]);
    }
    for (int idx = tid; idx < 64 * 64; idx += 256) {
        int e = idx >> 6, k = idx & 63;
        int eg = e0 + e;
        float v = (k < 50 && eg < E) ? basis[(size_t)eg * 50 + k] : 0.0f;
        hb[e * 72 + k] = f2b(v);
    }
    if (tid < 64) {
        int eg = e0 + tid;
        if (eg < E) {
            cc[tid] = 0.25f * (__cosf(e_ji[eg] * 0.31415926535897932f) + 1.0f);
            s_src[tid] = pairs[eg];
            s_dst[tid] = pairs[E + eg];
        } else { cc[tid] = 0.0f; s_src[tid] = 0; s_dst[tid] = 0; }
    }
    __syncthreads();

    const int l = tid & 63, w = tid >> 6;
    const int lr = l & 15, lg = l >> 4;

    f32x4 acc1[8] = {};
    for (int ks = 0; ks < 2; ++ks) {
        bf16x8 a = *reinterpret_cast<const bf16x8*>(
            &hb[(w * 16 + lr) * 72 + ks * 32 + lg * 8]);
        for (int n = 0; n < 8; ++n) {
            bf16x8 b = *reinterpret_cast<const bf16x8*>(
                &fw1_lds[(n * 16 + lr) * 72 + ks * 32 + lg * 8]);
            acc1[n] = __builtin_amdgcn_mfma_f32_16x16x32_bf16(a, b, acc1[n], 0, 0, 0);
        }
    }
    __syncthreads();

    for (int n = 0; n < 8; ++n) {
        int c = n * 16 + lr;
        float bv = fb1[c];
        for (int i = 0; i < 4; ++i) {
            int r = w * 16 + lg * 4 + i;
            hb[r * 136 + c] = f2b(ssp(acc1[n][i] + bv));
        }
    }
    __syncthreads();

    f32x4 acc2[8] = {};
    for (int ks = 0; ks < 4; ++ks) {
        bf16x8 a = *reinterpret_cast<const bf16x8*>(
            &hb[(w * 16 + lr) * 136 + ks * 32 + lg * 8]);
        for (int n = 0; n < 8; ++n) {
            bf16x8 b = *reinterpret_cast<const bf16x8*>(
                &fw2_lds[(n * 16 + lr) * 136 + ks * 32 + lg * 8]);
            acc2[n] = __builtin_amdgcn_mfma_f32_16x16x32_bf16(a, b, acc2[n], 0, 0, 0);
        }
    }

    for (int n = 0; n < 8; ++n) {
        int c = n * 16 + lr;
        float bv = fb2[c];
        for (int i = 0; i < 4; ++i) {
            int eloc = w * 16 + lg * 4 + i;
            if (e0 + eloc < E) {
                float Wv = (acc2[n][i] + bv) * cc[eloc];
                float val = xh[(size_t)s_src[eloc] * 128 + c] * Wv;
                unsafeAtomicAdd(&agg[(size_t)s_dst[eloc] * 128 + c], val);
            }
        }
    }
}

extern "C" void kernel_launch(void* const* d_in, const int* in_sizes, int n_in,
                              void* d_out, int out_size, void* d_ws, size_t ws_size,
                              hipStream_t stream) {
    const float* x      = (const float*)d_in[0];
    const int*   pairs  = (const int*)d_in[1];
    const float* e_ji   = (const float*)d_in[2];
    const float* basis  = (const float*)d_in[3];
    const float* fw1    = (const float*)d_in[4];
    const float* fb1    = (const float*)d_in[5];
    const float* fw2    = (const float*)d_in[6];
    const float* fb2    = (const float*)d_in[7];
    const float* w1     = (const float*)d_in[8];
    const float* w2     = (const float*)d_in[9];
    const float* b2     = (const float*)d_in[10];
    const float* w3     = (const float*)d_in[11];
    const float* b3     = (const float*)d_in[12];
    float* out = (float*)d_out;

    const int N = in_sizes[0] / 128;
    const int E = in_sizes[2];
    const int nodeBlocks = (N + 63) / 64;
    const int nchunks = (N + 255) / 256;
    char* ws = (char*)d_ws;

    size_t off = 0;
    auto nxt = [&](size_t bytes) {
        size_t o = off; off = (off + bytes + 255) & ~(size_t)255; return o;
    };
    u16*   Wb     = (u16*)  (ws + nxt((size_t)E * 128 * 2));
    u16*   xhb    = (u16*)  (ws + nxt((size_t)N * 128 * 2));
    u16*   aggb   = (u16*)  (ws + nxt((size_t)N * 128 * 2));
    u16*   wb     = (u16*)  (ws + nxt(81920 * 2));
    int*   deg    = (int*)  (ws + nxt((size_t)N * 4));
    int*   incl   = (int*)  (ws + nxt((size_t)N * 4));
    int*   rowst  = (int*)  (ws + nxt((size_t)N * 4));
    int*   cursor = (int*)  (ws + nxt((size_t)N * 4));
    int*   bsum   = (int*)  (ws + nxt(1024));
    int*   esrc   = (int*)  (ws + nxt((size_t)E * 4));
    int*   epos   = (int*)  (ws + nxt((size_t)E * 4));
    const size_t needed = off;

    const u16* fw1b = wb;
    const u16* fw2b = wb + 8192;
    const u16* w1b  = wb + 8192 + 16384;
    const u16* w2b  = wb + 8192 + 32768;
    const u16* w3b  = wb + 8192 + 49152;

    if (ws_size >= needed && nchunks <= 256) {
        prep_weights<<<288, 256, 0, stream>>>(fw1, fw2, w1, w2, w3, wb);
        hipMemsetAsync(deg, 0, (size_t)N * 4, stream);

        linear128<0, 1><<<nodeBlocks, 256, 0, stream>>>(x, w1b, nullptr, xhb, N);

        hist_kernel<<<(E + 255) / 256, 256, 0, stream>>>(pairs, deg, E);
        scan_a<<<nchunks, 256, 0, stream>>>(deg, incl, bsum, N);
        scan_b<<<1, 256, 0, stream>>>(bsum, nchunks);
        scan_c<<<nchunks, 256, 0, stream>>>(incl, deg, bsum, rowst, cursor, N);
        fill_kernel<<<(E + 255) / 256, 256, 0, stream>>>(pairs, cursor, esrc, epos, E);

        const int nTiles = (E + 31) / 32;
        const int gridE = nTiles < 1024 ? nTiles : 1024;
        edge_mlp<<<gridE, 512, 0, stream>>>(basis, e_ji, fw1b, fw2b,
                                            fb1, fb2, epos, Wb, E, nTiles, gridE);

        aggregate<<<(N + 3) / 4, 256, 0, stream>>>(Wb, xhb, rowst, deg,
                                                   esrc, aggb, N);

        const int ntT = (N + 31) / 32;
        const int gridT = ntT < 1024 ? ntT : 1024;
        fused_tail<<<gridT, 256, 0, stream>>>(aggb, w2b, w3b, b2, b3, out,
                                              N, ntT, gridT);
    } else {
        const size_t nodeBytes = (size_t)N * 128 * sizeof(float);
        float* xhf   = (float*)ws;
        float* aggf  = (float*)(ws + nodeBytes);
        u16*   wbf   = (u16*)(ws + 2 * nodeBytes);
        const u16* ffw1b = wbf;
        const u16* ffw2b = wbf + 8192;
        const u16* fw1bw = wbf + 8192 + 16384;
        const u16* fw2bw = wbf + 8192 + 32768;
        const u16* fw3bw = wbf + 8192 + 49152;

        prep_weights<<<288, 256, 0, stream>>>(fw1, fw2, w1, w2, w3, wbf);
        hipMemsetAsync(aggf, 0, nodeBytes, stream);
        linear128<0, 0><<<nodeBlocks, 256, 0, stream>>>(x, fw1bw, nullptr, xhf, N);
        edge_kernel<<<(E + 63) / 64, 256, 0, stream>>>(basis, e_ji, pairs, xhf,
                                                       ffw1b, ffw2b, fb1, fb2, aggf, E);
        linear128<1, 0><<<nodeBlocks, 256, 0, stream>>>(aggf, fw2bw, b2, out, N);
        linear128<0, 0><<<nodeBlocks, 256, 0, stream>>>(out, fw3bw, b3, out, N);
    }
}